// Round 1
// baseline (687.201 us; speedup 1.0000x reference)
//
#include <hip/hip_runtime.h>

typedef __bf16 bf16;
typedef bf16 bf16x8 __attribute__((ext_vector_type(8)));
typedef bf16 bf16x4 __attribute__((ext_vector_type(4)));
typedef float f32x4 __attribute__((ext_vector_type(4)));

#define C_DIM 1024
#define T_DIM 2048
#define B_DIM 4
#define H_DIM 4096

// ---------------------------------------------------------------------------
// async global -> LDS, 16B per lane. LDS dest is wave-uniform base + lane*16.
// ---------------------------------------------------------------------------
__device__ inline void gld_lds16(const bf16* g, bf16* l) {
    __builtin_amdgcn_global_load_lds(
        (const __attribute__((address_space(1))) unsigned int*)g,
        (__attribute__((address_space(3))) unsigned int*)l,
        16, 0, 0);
}

// ---------------------------------------------------------------------------
// GEMM: C[M,N] = alpha * A[M,K] @ Bt[N,K]^T (+ bias) (+ gelu | + resid)
// EPI: 0 = alpha*acc + bias(optional)           -> OutT
//      1 = gelu(acc + bias)                     -> OutT (bf16)
//      2 = acc + bias + resid (fp32 residual)   -> OutT (float)
// 128x128 tile, 4 waves (2x2), each wave 4x4 of 16x16x32 bf16 MFMA, BK=64.
// All of M,N divisible by 128, K divisible by 64. Batched via blockIdx.z.
// ---------------------------------------------------------------------------
template <int EPI, typename OutT>
__launch_bounds__(256)
__global__ void gemm_bt(const bf16* __restrict__ A, int lda, long long sA,
                        const bf16* __restrict__ Bt, int ldb, long long sB,
                        OutT* __restrict__ Cout, int ldc, long long sC,
                        const float* __restrict__ bias,
                        const float* __restrict__ resid, long long sR,
                        float alpha, int K) {
    const int z = blockIdx.z;
    A += (long long)z * sA;
    Bt += (long long)z * sB;
    Cout += (long long)z * sC;
    if (resid) resid += (long long)z * sR;

    const int rowBase = blockIdx.x * 128;
    const int colBase = blockIdx.y * 128;

    __shared__ __align__(16) bf16 As[128 * 64];
    __shared__ __align__(16) bf16 Bs[128 * 64];

    const int tid = threadIdx.x;
    const int w = tid >> 6, lane = tid & 63;
    const int wm = w & 1, wn = w >> 1;
    const int lr = lane & 15, lq = lane >> 4;

    // staging assignments: 1024 chunks of 16B per matrix, 4 per thread
    const bf16* aG[4];
    const bf16* bG[4];
    bf16* aL[4];
    bf16* bL[4];
#pragma unroll
    for (int t = 0; t < 4; t++) {
        int c = t * 256 + tid;              // chunk id = t*256 + w*64 + lane
        aG[t] = A + (size_t)(rowBase + (c >> 3)) * lda + (c & 7) * 8;
        bG[t] = Bt + (size_t)(colBase + (c >> 3)) * ldb + (c & 7) * 8;
        int ubase = (t * 256 + w * 64) * 8; // wave-uniform LDS base (elements)
        aL[t] = As + ubase;
        bL[t] = Bs + ubase;
    }

    f32x4 acc[4][4] = {};

    for (int k0 = 0; k0 < K; k0 += 64) {
        __syncthreads();
#pragma unroll
        for (int t = 0; t < 4; t++) {
            gld_lds16(aG[t], aL[t]);
            gld_lds16(bG[t], bL[t]);
            aG[t] += 64;
            bG[t] += 64;
        }
        __syncthreads();
#pragma unroll
        for (int ks = 0; ks < 2; ks++) {
            bf16x8 af[4], bfv[4];
#pragma unroll
            for (int i = 0; i < 4; i++)
                af[i] = *(const bf16x8*)(As + (wm * 64 + i * 16 + lr) * 64 + ks * 32 + lq * 8);
#pragma unroll
            for (int j = 0; j < 4; j++)
                bfv[j] = *(const bf16x8*)(Bs + (wn * 64 + j * 16 + lr) * 64 + ks * 32 + lq * 8);
#pragma unroll
            for (int i = 0; i < 4; i++)
#pragma unroll
                for (int j = 0; j < 4; j++)
                    acc[i][j] = __builtin_amdgcn_mfma_f32_16x16x32_bf16(af[i], bfv[j], acc[i][j], 0, 0, 0);
        }
    }

    // epilogue. C/D layout: col = lane&15, row = (lane>>4)*4 + reg
#pragma unroll
    for (int i = 0; i < 4; i++) {
        const int r0 = rowBase + wm * 64 + i * 16 + lq * 4;
#pragma unroll
        for (int j = 0; j < 4; j++) {
            const int col = colBase + wn * 64 + j * 16 + lr;
            const float bval = bias ? bias[col] : 0.0f;
#pragma unroll
            for (int r = 0; r < 4; r++) {
                float v = acc[i][j][r] * alpha + bval;
                if constexpr (EPI == 1) {
                    float u = v;
                    float t = tanhf(0.7978845608028654f * (u + 0.044715f * u * u * u));
                    v = 0.5f * u * (1.0f + t);
                }
                if constexpr (EPI == 2) {
                    v += resid[(size_t)(r0 + r) * ldc + col];
                }
                Cout[(size_t)(r0 + r) * ldc + col] = (OutT)v;
            }
        }
    }
}

// ---------------------------------------------------------------------------
// LayerNorm over last dim (C=1024), fp32 in -> bf16 out. One block per row.
// ---------------------------------------------------------------------------
__launch_bounds__(256)
__global__ void ln_kernel(const float* __restrict__ x, const float* __restrict__ g,
                          const float* __restrict__ b, bf16* __restrict__ out) {
    __shared__ float red[4];
    const int row = blockIdx.x;
    const int tid = threadIdx.x;
    const float4* xr = (const float4*)(x + (size_t)row * C_DIM);
    float4 v = xr[tid];
    float s = v.x + v.y + v.z + v.w;
#pragma unroll
    for (int m = 32; m; m >>= 1) s += __shfl_xor(s, m, 64);
    if ((tid & 63) == 0) red[tid >> 6] = s;
    __syncthreads();
    const float mu = (red[0] + red[1] + red[2] + red[3]) * (1.0f / C_DIM);
    const float dx = v.x - mu, dy = v.y - mu, dz = v.z - mu, dw = v.w - mu;
    float q = dx * dx + dy * dy + dz * dz + dw * dw;
#pragma unroll
    for (int m = 32; m; m >>= 1) q += __shfl_xor(q, m, 64);
    __syncthreads();
    if ((tid & 63) == 0) red[tid >> 6] = q;
    __syncthreads();
    const float var = (red[0] + red[1] + red[2] + red[3]) * (1.0f / C_DIM);
    const float rs = rsqrtf(var + 1e-5f);
    const float4 gg = ((const float4*)g)[tid];
    const float4 bb = ((const float4*)b)[tid];
    bf16x4 o;
    o[0] = (bf16)(dx * rs * gg.x + bb.x);
    o[1] = (bf16)(dy * rs * gg.y + bb.y);
    o[2] = (bf16)(dz * rs * gg.z + bb.z);
    o[3] = (bf16)(dw * rs * gg.w + bb.w);
    ((bf16x4*)(out + (size_t)row * C_DIM))[tid] = o;
}

// ---------------------------------------------------------------------------
// Row softmax: S row (T=2048 fp32) -> P row (bf16). One block per row.
// ---------------------------------------------------------------------------
__launch_bounds__(256)
__global__ void softmax_kernel(const float* __restrict__ S, bf16* __restrict__ P) {
    __shared__ float red[4];
    const size_t base = (size_t)blockIdx.x * T_DIM;
    const int tid = threadIdx.x;
    const float4* sr = (const float4*)(S + base);
    float4 v0 = sr[tid];
    float4 v1 = sr[tid + 256];
    float mx = fmaxf(fmaxf(fmaxf(v0.x, v0.y), fmaxf(v0.z, v0.w)),
                     fmaxf(fmaxf(v1.x, v1.y), fmaxf(v1.z, v1.w)));
#pragma unroll
    for (int m = 32; m; m >>= 1) mx = fmaxf(mx, __shfl_xor(mx, m, 64));
    if ((tid & 63) == 0) red[tid >> 6] = mx;
    __syncthreads();
    mx = fmaxf(fmaxf(red[0], red[1]), fmaxf(red[2], red[3]));
    float e[8];
    e[0] = __expf(v0.x - mx); e[1] = __expf(v0.y - mx);
    e[2] = __expf(v0.z - mx); e[3] = __expf(v0.w - mx);
    e[4] = __expf(v1.x - mx); e[5] = __expf(v1.y - mx);
    e[6] = __expf(v1.z - mx); e[7] = __expf(v1.w - mx);
    float s = e[0] + e[1] + e[2] + e[3] + e[4] + e[5] + e[6] + e[7];
#pragma unroll
    for (int m = 32; m; m >>= 1) s += __shfl_xor(s, m, 64);
    __syncthreads();
    if ((tid & 63) == 0) red[tid >> 6] = s;
    __syncthreads();
    const float inv = 1.0f / (red[0] + red[1] + red[2] + red[3]);
    bf16x4 p0, p1;
#pragma unroll
    for (int i = 0; i < 4; i++) {
        p0[i] = (bf16)(e[i] * inv);
        p1[i] = (bf16)(e[4 + i] * inv);
    }
    ((bf16x4*)(P + base))[tid] = p0;
    ((bf16x4*)(P + base))[tid + 256] = p1;
}

// ---------------------------------------------------------------------------
// Transpose + convert: src fp32 [R, Cc] (ld=Cc) -> dst bf16 [Cc, R] (ld=R)
// ---------------------------------------------------------------------------
__global__ void transpose_f2b(const float* __restrict__ src, bf16* __restrict__ dst,
                              int R, int Cc) {
    __shared__ float tile[32][33];
    const int bx = blockIdx.x * 32;  // col of src
    const int by = blockIdx.y * 32;  // row of src
    const int tx = threadIdx.x, ty = threadIdx.y;
    for (int i = ty; i < 32; i += 8)
        tile[i][tx] = src[(size_t)(by + i) * Cc + bx + tx];
    __syncthreads();
    for (int i = ty; i < 32; i += 8)
        dst[(size_t)(bx + i) * R + by + tx] = (bf16)tile[tx][i];
}

// Transpose bf16 [R, Cc] (ld=ldsrc) -> bf16 [Cc, R] (ld=R), batched via z.
__global__ void transpose_b2b(const bf16* __restrict__ src, int ldsrc, long long sstride,
                              bf16* __restrict__ dst, long long dstride, int R) {
    __shared__ bf16 tile[32][33];
    src += (long long)blockIdx.z * sstride;
    dst += (long long)blockIdx.z * dstride;
    const int bx = blockIdx.x * 32;
    const int by = blockIdx.y * 32;
    const int tx = threadIdx.x, ty = threadIdx.y;
    for (int i = ty; i < 32; i += 8)
        tile[i][tx] = src[(size_t)(by + i) * ldsrc + bx + tx];
    __syncthreads();
    for (int i = ty; i < 32; i += 8)
        dst[(size_t)(bx + i) * R + by + tx] = tile[tx][i];
}

// ---------------------------------------------------------------------------
extern "C" void kernel_launch(void* const* d_in, const int* in_sizes, int n_in,
                              void* d_out, int out_size, void* d_ws, size_t ws_size,
                              hipStream_t stream) {
    const float* x      = (const float*)d_in[0];
    const float* ln1_g  = (const float*)d_in[1];
    const float* ln1_b  = (const float*)d_in[2];
    const float* w_attn = (const float*)d_in[3];
    const float* b_attn = (const float*)d_in[4];
    const float* w_proj = (const float*)d_in[5];
    const float* b_proj = (const float*)d_in[6];
    const float* ln2_g  = (const float*)d_in[7];
    const float* ln2_b  = (const float*)d_in[8];
    const float* w_fc   = (const float*)d_in[9];
    const float* b_fc   = (const float*)d_in[10];
    const float* w_mlp  = (const float*)d_in[11];
    const float* b_mlp  = (const float*)d_in[12];
    float* out = (float*)d_out;

    const int M = B_DIM * T_DIM;  // 8192

    char* base = (char*)d_ws;
    size_t off = 0;
    auto alloc = [&](size_t bytes) -> char* {
        char* p = base + off;
        off += (bytes + 255) & ~(size_t)255;
        return p;
    };
    bf16* wT_attn = (bf16*)alloc((size_t)3072 * 1024 * 2);
    bf16* wT_proj = (bf16*)alloc((size_t)1024 * 1024 * 2);
    bf16* wT_fc   = (bf16*)alloc((size_t)4096 * 1024 * 2);
    bf16* wT_mlp  = (bf16*)alloc((size_t)1024 * 4096 * 2);
    bf16* h       = (bf16*)alloc((size_t)M * 1024 * 2);        // h1, reused as h2
    bf16* qkv     = (bf16*)alloc((size_t)M * 3072 * 2);
    bf16* vT      = (bf16*)alloc((size_t)B_DIM * 1024 * 2048 * 2);
    float* S      = (float*)alloc((size_t)B_DIM * 2048 * 2048 * 4);
    bf16* P       = (bf16*)alloc((size_t)B_DIM * 2048 * 2048 * 2);
    bf16* y       = (bf16*)alloc((size_t)M * 1024 * 2);
    float* x2     = (float*)alloc((size_t)M * 1024 * 4);
    bf16* act     = (bf16*)S;  // alias: S dead after softmax; sizes match (67MB)

    const dim3 tb(32, 8);

    // weight transpose+convert (per call: inputs restored every launch)
    transpose_f2b<<<dim3(3072 / 32, 1024 / 32, 1), tb, 0, stream>>>(w_attn, wT_attn, 1024, 3072);
    transpose_f2b<<<dim3(1024 / 32, 1024 / 32, 1), tb, 0, stream>>>(w_proj, wT_proj, 1024, 1024);
    transpose_f2b<<<dim3(4096 / 32, 1024 / 32, 1), tb, 0, stream>>>(w_fc, wT_fc, 1024, 4096);
    transpose_f2b<<<dim3(1024 / 32, 4096 / 32, 1), tb, 0, stream>>>(w_mlp, wT_mlp, 4096, 1024);

    // h = LN1(x)
    ln_kernel<<<M, 256, 0, stream>>>(x, ln1_g, ln1_b, h);

    // qkv = h @ w_attn + b_attn   [8192, 3072]
    gemm_bt<0, bf16><<<dim3(64, 24, 1), 256, 0, stream>>>(
        h, 1024, 0, wT_attn, 1024, 0, qkv, 3072, 0, b_attn, nullptr, 0, 1.0f, 1024);

    // vT[b] = v[b]^T   (v = qkv cols [2C,3C))
    transpose_b2b<<<dim3(1024 / 32, 2048 / 32, B_DIM), tb, 0, stream>>>(
        qkv + 2 * C_DIM, 3072, (long long)T_DIM * 3072, vT, (long long)C_DIM * T_DIM, T_DIM);

    // S[b] = q[b] @ k[b]^T * (1/32)   [2048, 2048] fp32
    gemm_bt<0, float><<<dim3(16, 16, B_DIM), 256, 0, stream>>>(
        qkv, 3072, (long long)T_DIM * 3072,
        qkv + C_DIM, 3072, (long long)T_DIM * 3072,
        S, 2048, (long long)T_DIM * T_DIM, nullptr, nullptr, 0, 0.03125f, 1024);

    // P = softmax(S) rows
    softmax_kernel<<<B_DIM * T_DIM, 256, 0, stream>>>(S, P);

    // y[b] = P[b] @ v[b]   [2048, 1024] bf16
    gemm_bt<0, bf16><<<dim3(16, 8, B_DIM), 256, 0, stream>>>(
        P, 2048, (long long)T_DIM * T_DIM,
        vT, 2048, (long long)C_DIM * T_DIM,
        y, 1024, (long long)T_DIM * C_DIM, nullptr, nullptr, 0, 1.0f, 2048);

    // x2 = y @ w_proj + b_proj + x   [8192, 1024] fp32
    gemm_bt<2, float><<<dim3(64, 8, 1), 256, 0, stream>>>(
        y, 1024, 0, wT_proj, 1024, 0, x2, 1024, 0, b_proj, x, 0, 1.0f, 1024);

    // h2 = LN2(x2)  (reuse h buffer)
    ln_kernel<<<M, 256, 0, stream>>>(x2, ln2_g, ln2_b, h);

    // act = gelu(h2 @ w_fc + b_fc)   [8192, 4096] bf16
    gemm_bt<1, bf16><<<dim3(64, 32, 1), 256, 0, stream>>>(
        h, 1024, 0, wT_fc, 1024, 0, act, 4096, 0, b_fc, nullptr, 0, 1.0f, 1024);

    // out = act @ w_mlp_proj + b_mlp_proj + x2   [8192, 1024] fp32
    gemm_bt<2, float><<<dim3(64, 8, 1), 256, 0, stream>>>(
        act, 4096, 0, wT_mlp, 4096, 0, out, 1024, 0, b_mlp, x2, 0, 1.0f, 4096);
}

// Round 2
// 587.583 us; speedup vs baseline: 1.1695x; 1.1695x over previous
//
#include <hip/hip_runtime.h>

typedef __bf16 bf16;
typedef bf16 bf16x8 __attribute__((ext_vector_type(8)));
typedef bf16 bf16x4 __attribute__((ext_vector_type(4)));
typedef float f32x4 __attribute__((ext_vector_type(4)));

#define C_DIM 1024
#define T_DIM 2048
#define B_DIM 4
#define H_DIM 4096

// ---------------------------------------------------------------------------
// async global -> LDS, 16B per lane. LDS dest is wave-uniform base + lane*16.
// ---------------------------------------------------------------------------
__device__ inline void gld_lds16(const bf16* g, bf16* l) {
    __builtin_amdgcn_global_load_lds(
        (const __attribute__((address_space(1))) unsigned int*)g,
        (__attribute__((address_space(3))) unsigned int*)l,
        16, 0, 0);
}

// fast tanh-gelu: u * sigmoid(1.5957692*u + 0.07135481*u^3)
__device__ inline float fast_gelu(float u) {
    float k2 = 1.5957691216057308f * u + 0.07135480895843475f * u * u * u;
    float t = __expf(-k2);
    return u * __builtin_amdgcn_rcpf(1.0f + t);
}

// ---------------------------------------------------------------------------
// GEMM: C[M,N] = alpha * A[M,K] @ Bt[N,K]^T (+ bias) (+ gelu | + resid)
// EPI: 0 = alpha*acc + bias(optional)           -> OutT
//      1 = gelu(acc + bias)                     -> OutT (bf16)
//      2 = acc + bias + resid (fp32 residual)   -> OutT (float)
// 128x128 tile, 4 waves (2x2), each wave 4x4 of 16x16x32 bf16 MFMA, BK=64.
// LDS layout XOR-swizzled: slot (row, c) holds global chunk (row, c^(row&7))
// -> row stride 128B no longer aliases all rows onto one 4-bank group.
// ---------------------------------------------------------------------------
template <int EPI, typename OutT>
__launch_bounds__(256)
__global__ void gemm_bt(const bf16* __restrict__ A, int lda, long long sA,
                        const bf16* __restrict__ Bt, int ldb, long long sB,
                        OutT* __restrict__ Cout, int ldc, long long sC,
                        const float* __restrict__ bias,
                        const float* __restrict__ resid, long long sR,
                        float alpha, int K) {
    const int z = blockIdx.z;
    A += (long long)z * sA;
    Bt += (long long)z * sB;
    Cout += (long long)z * sC;
    if (resid) resid += (long long)z * sR;

    const int rowBase = blockIdx.x * 128;
    const int colBase = blockIdx.y * 128;

    __shared__ __align__(16) bf16 As[128 * 64];
    __shared__ __align__(16) bf16 Bs[128 * 64];

    const int tid = threadIdx.x;
    const int w = tid >> 6, lane = tid & 63;
    const int wm = w & 1, wn = w >> 1;
    const int lr = lane & 15, lq = lane >> 4;

    // staging: 1024 chunks of 16B per matrix, 4 per thread, XOR-swizzled src
    const bf16* aG[4];
    const bf16* bG[4];
    bf16* aL[4];
    bf16* bL[4];
#pragma unroll
    for (int t = 0; t < 4; t++) {
        int p = t * 256 + tid;               // LDS slot id = t*256 + w*64 + lane
        int prow = p >> 3, pcol = p & 7;
        int gcol = pcol ^ (prow & 7);        // swizzle: which global chunk lands here
        aG[t] = A + (size_t)(rowBase + prow) * lda + gcol * 8;
        bG[t] = Bt + (size_t)(colBase + prow) * ldb + gcol * 8;
        int ubase = (t * 256 + w * 64) * 8;  // wave-uniform LDS base (elements)
        aL[t] = As + ubase;
        bL[t] = Bs + ubase;
    }

    f32x4 acc[4][4] = {};

    for (int k0 = 0; k0 < K; k0 += 64) {
        __syncthreads();
#pragma unroll
        for (int t = 0; t < 4; t++) {
            gld_lds16(aG[t], aL[t]);
            gld_lds16(bG[t], bL[t]);
            aG[t] += 64;
            bG[t] += 64;
        }
        __syncthreads();
#pragma unroll
        for (int ks = 0; ks < 2; ks++) {
            bf16x8 af[4], bfv[4];
#pragma unroll
            for (int i = 0; i < 4; i++) {
                int r = wm * 64 + i * 16 + lr;
                int cc = (ks << 2) | lq;
                af[i] = *(const bf16x8*)(As + r * 64 + ((cc ^ (r & 7)) << 3));
            }
#pragma unroll
            for (int j = 0; j < 4; j++) {
                int r = wn * 64 + j * 16 + lr;
                int cc = (ks << 2) | lq;
                bfv[j] = *(const bf16x8*)(Bs + r * 64 + ((cc ^ (r & 7)) << 3));
            }
#pragma unroll
            for (int i = 0; i < 4; i++)
#pragma unroll
                for (int j = 0; j < 4; j++)
                    acc[i][j] = __builtin_amdgcn_mfma_f32_16x16x32_bf16(af[i], bfv[j], acc[i][j], 0, 0, 0);
        }
    }

    // epilogue. C/D layout: col = lane&15, row = (lane>>4)*4 + reg
    float bval[4];
#pragma unroll
    for (int j = 0; j < 4; j++)
        bval[j] = bias ? bias[colBase + wn * 64 + j * 16 + lr] : 0.0f;
#pragma unroll
    for (int i = 0; i < 4; i++) {
        const int r0 = rowBase + wm * 64 + i * 16 + lq * 4;
#pragma unroll
        for (int j = 0; j < 4; j++) {
            const int col = colBase + wn * 64 + j * 16 + lr;
#pragma unroll
            for (int r = 0; r < 4; r++) {
                float v = acc[i][j][r] * alpha + bval[j];
                if constexpr (EPI == 1) {
                    v = fast_gelu(v);
                }
                if constexpr (EPI == 2) {
                    v += resid[(size_t)(r0 + r) * ldc + col];
                }
                Cout[(size_t)(r0 + r) * ldc + col] = (OutT)v;
            }
        }
    }
}

// ---------------------------------------------------------------------------
// LayerNorm over last dim (C=1024), fp32 in -> bf16 out. One block per row.
// ---------------------------------------------------------------------------
__launch_bounds__(256)
__global__ void ln_kernel(const float* __restrict__ x, const float* __restrict__ g,
                          const float* __restrict__ b, bf16* __restrict__ out) {
    __shared__ float red[4];
    const int row = blockIdx.x;
    const int tid = threadIdx.x;
    const float4* xr = (const float4*)(x + (size_t)row * C_DIM);
    float4 v = xr[tid];
    float s = v.x + v.y + v.z + v.w;
#pragma unroll
    for (int m = 32; m; m >>= 1) s += __shfl_xor(s, m, 64);
    if ((tid & 63) == 0) red[tid >> 6] = s;
    __syncthreads();
    const float mu = (red[0] + red[1] + red[2] + red[3]) * (1.0f / C_DIM);
    const float dx = v.x - mu, dy = v.y - mu, dz = v.z - mu, dw = v.w - mu;
    float q = dx * dx + dy * dy + dz * dz + dw * dw;
#pragma unroll
    for (int m = 32; m; m >>= 1) q += __shfl_xor(q, m, 64);
    __syncthreads();
    if ((tid & 63) == 0) red[tid >> 6] = q;
    __syncthreads();
    const float var = (red[0] + red[1] + red[2] + red[3]) * (1.0f / C_DIM);
    const float rs = rsqrtf(var + 1e-5f);
    const float4 gg = ((const float4*)g)[tid];
    const float4 bb = ((const float4*)b)[tid];
    bf16x4 o;
    o[0] = (bf16)(dx * rs * gg.x + bb.x);
    o[1] = (bf16)(dy * rs * gg.y + bb.y);
    o[2] = (bf16)(dz * rs * gg.z + bb.z);
    o[3] = (bf16)(dw * rs * gg.w + bb.w);
    ((bf16x4*)(out + (size_t)row * C_DIM))[tid] = o;
}

// ---------------------------------------------------------------------------
// Row softmax: S row (T=2048 fp32) -> P row (bf16). One block per row.
// ---------------------------------------------------------------------------
__launch_bounds__(256)
__global__ void softmax_kernel(const float* __restrict__ S, bf16* __restrict__ P) {
    __shared__ float red[4];
    const size_t base = (size_t)blockIdx.x * T_DIM;
    const int tid = threadIdx.x;
    const float4* sr = (const float4*)(S + base);
    float4 v0 = sr[tid];
    float4 v1 = sr[tid + 256];
    float mx = fmaxf(fmaxf(fmaxf(v0.x, v0.y), fmaxf(v0.z, v0.w)),
                     fmaxf(fmaxf(v1.x, v1.y), fmaxf(v1.z, v1.w)));
#pragma unroll
    for (int m = 32; m; m >>= 1) mx = fmaxf(mx, __shfl_xor(mx, m, 64));
    if ((tid & 63) == 0) red[tid >> 6] = mx;
    __syncthreads();
    mx = fmaxf(fmaxf(red[0], red[1]), fmaxf(red[2], red[3]));
    float e[8];
    e[0] = __expf(v0.x - mx); e[1] = __expf(v0.y - mx);
    e[2] = __expf(v0.z - mx); e[3] = __expf(v0.w - mx);
    e[4] = __expf(v1.x - mx); e[5] = __expf(v1.y - mx);
    e[6] = __expf(v1.z - mx); e[7] = __expf(v1.w - mx);
    float s = e[0] + e[1] + e[2] + e[3] + e[4] + e[5] + e[6] + e[7];
#pragma unroll
    for (int m = 32; m; m >>= 1) s += __shfl_xor(s, m, 64);
    __syncthreads();
    if ((tid & 63) == 0) red[tid >> 6] = s;
    __syncthreads();
    const float inv = 1.0f / (red[0] + red[1] + red[2] + red[3]);
    bf16x4 p0, p1;
#pragma unroll
    for (int i = 0; i < 4; i++) {
        p0[i] = (bf16)(e[i] * inv);
        p1[i] = (bf16)(e[4 + i] * inv);
    }
    ((bf16x4*)(P + base))[tid] = p0;
    ((bf16x4*)(P + base))[tid + 256] = p1;
}

// ---------------------------------------------------------------------------
// Transpose + convert: src fp32 [R, Cc] (ld=Cc) -> dst bf16 [Cc, R] (ld=R)
// ---------------------------------------------------------------------------
__global__ void transpose_f2b(const float* __restrict__ src, bf16* __restrict__ dst,
                              int R, int Cc) {
    __shared__ float tile[32][33];
    const int bx = blockIdx.x * 32;  // col of src
    const int by = blockIdx.y * 32;  // row of src
    const int tx = threadIdx.x, ty = threadIdx.y;
    for (int i = ty; i < 32; i += 8)
        tile[i][tx] = src[(size_t)(by + i) * Cc + bx + tx];
    __syncthreads();
    for (int i = ty; i < 32; i += 8)
        dst[(size_t)(bx + i) * R + by + tx] = (bf16)tile[tx][i];
}

// Transpose bf16 [R, Cc] (ld=ldsrc) -> bf16 [Cc, R] (ld=R), batched via z.
__global__ void transpose_b2b(const bf16* __restrict__ src, int ldsrc, long long sstride,
                              bf16* __restrict__ dst, long long dstride, int R) {
    __shared__ bf16 tile[32][33];
    src += (long long)blockIdx.z * sstride;
    dst += (long long)blockIdx.z * dstride;
    const int bx = blockIdx.x * 32;
    const int by = blockIdx.y * 32;
    const int tx = threadIdx.x, ty = threadIdx.y;
    for (int i = ty; i < 32; i += 8)
        tile[i][tx] = src[(size_t)(by + i) * ldsrc + bx + tx];
    __syncthreads();
    for (int i = ty; i < 32; i += 8)
        dst[(size_t)(bx + i) * R + by + tx] = tile[tx][i];
}

// ---------------------------------------------------------------------------
extern "C" void kernel_launch(void* const* d_in, const int* in_sizes, int n_in,
                              void* d_out, int out_size, void* d_ws, size_t ws_size,
                              hipStream_t stream) {
    const float* x      = (const float*)d_in[0];
    const float* ln1_g  = (const float*)d_in[1];
    const float* ln1_b  = (const float*)d_in[2];
    const float* w_attn = (const float*)d_in[3];
    const float* b_attn = (const float*)d_in[4];
    const float* w_proj = (const float*)d_in[5];
    const float* b_proj = (const float*)d_in[6];
    const float* ln2_g  = (const float*)d_in[7];
    const float* ln2_b  = (const float*)d_in[8];
    const float* w_fc   = (const float*)d_in[9];
    const float* b_fc   = (const float*)d_in[10];
    const float* w_mlp  = (const float*)d_in[11];
    const float* b_mlp  = (const float*)d_in[12];
    float* out = (float*)d_out;

    const int M = B_DIM * T_DIM;  // 8192

    char* base = (char*)d_ws;
    size_t off = 0;
    auto alloc = [&](size_t bytes) -> char* {
        char* p = base + off;
        off += (bytes + 255) & ~(size_t)255;
        return p;
    };
    bf16* wT_attn = (bf16*)alloc((size_t)3072 * 1024 * 2);
    bf16* wT_proj = (bf16*)alloc((size_t)1024 * 1024 * 2);
    bf16* wT_fc   = (bf16*)alloc((size_t)4096 * 1024 * 2);
    bf16* wT_mlp  = (bf16*)alloc((size_t)1024 * 4096 * 2);
    bf16* h       = (bf16*)alloc((size_t)M * 1024 * 2);        // h1, reused as h2
    bf16* qkv     = (bf16*)alloc((size_t)M * 3072 * 2);
    bf16* vT      = (bf16*)alloc((size_t)B_DIM * 1024 * 2048 * 2);
    float* S      = (float*)alloc((size_t)B_DIM * 2048 * 2048 * 4);
    bf16* P       = (bf16*)alloc((size_t)B_DIM * 2048 * 2048 * 2);
    bf16* y       = (bf16*)alloc((size_t)M * 1024 * 2);
    float* x2     = (float*)alloc((size_t)M * 1024 * 4);
    bf16* act     = (bf16*)S;  // alias: S dead after softmax; sizes match (67MB)

    const dim3 tb(32, 8);

    // weight transpose+convert (per call: inputs restored every launch)
    transpose_f2b<<<dim3(3072 / 32, 1024 / 32, 1), tb, 0, stream>>>(w_attn, wT_attn, 1024, 3072);
    transpose_f2b<<<dim3(1024 / 32, 1024 / 32, 1), tb, 0, stream>>>(w_proj, wT_proj, 1024, 1024);
    transpose_f2b<<<dim3(4096 / 32, 1024 / 32, 1), tb, 0, stream>>>(w_fc, wT_fc, 1024, 4096);
    transpose_f2b<<<dim3(1024 / 32, 4096 / 32, 1), tb, 0, stream>>>(w_mlp, wT_mlp, 4096, 1024);

    // h = LN1(x)
    ln_kernel<<<M, 256, 0, stream>>>(x, ln1_g, ln1_b, h);

    // qkv = h @ w_attn + b_attn   [8192, 3072]
    gemm_bt<0, bf16><<<dim3(64, 24, 1), 256, 0, stream>>>(
        h, 1024, 0, wT_attn, 1024, 0, qkv, 3072, 0, b_attn, nullptr, 0, 1.0f, 1024);

    // vT[b] = v[b]^T   (v = qkv cols [2C,3C))
    transpose_b2b<<<dim3(1024 / 32, 2048 / 32, B_DIM), tb, 0, stream>>>(
        qkv + 2 * C_DIM, 3072, (long long)T_DIM * 3072, vT, (long long)C_DIM * T_DIM, T_DIM);

    // S[b] = q[b] @ k[b]^T * (1/32)   [2048, 2048] fp32
    gemm_bt<0, float><<<dim3(16, 16, B_DIM), 256, 0, stream>>>(
        qkv, 3072, (long long)T_DIM * 3072,
        qkv + C_DIM, 3072, (long long)T_DIM * 3072,
        S, 2048, (long long)T_DIM * T_DIM, nullptr, nullptr, 0, 0.03125f, 1024);

    // P = softmax(S) rows
    softmax_kernel<<<B_DIM * T_DIM, 256, 0, stream>>>(S, P);

    // y[b] = P[b] @ v[b]   [2048, 1024] bf16
    gemm_bt<0, bf16><<<dim3(16, 8, B_DIM), 256, 0, stream>>>(
        P, 2048, (long long)T_DIM * T_DIM,
        vT, 2048, (long long)C_DIM * T_DIM,
        y, 1024, (long long)T_DIM * C_DIM, nullptr, nullptr, 0, 1.0f, 2048);

    // x2 = y @ w_proj + b_proj + x   [8192, 1024] fp32
    gemm_bt<2, float><<<dim3(64, 8, 1), 256, 0, stream>>>(
        y, 1024, 0, wT_proj, 1024, 0, x2, 1024, 0, b_proj, x, 0, 1.0f, 1024);

    // h2 = LN2(x2)  (reuse h buffer)
    ln_kernel<<<M, 256, 0, stream>>>(x2, ln2_g, ln2_b, h);

    // act = gelu(h2 @ w_fc + b_fc)   [8192, 4096] bf16
    gemm_bt<1, bf16><<<dim3(64, 32, 1), 256, 0, stream>>>(
        h, 1024, 0, wT_fc, 1024, 0, act, 4096, 0, b_fc, nullptr, 0, 1.0f, 1024);

    // out = act @ w_mlp_proj + b_mlp_proj + x2   [8192, 1024] fp32
    gemm_bt<2, float><<<dim3(64, 8, 1), 256, 0, stream>>>(
        act, 4096, 0, wT_mlp, 4096, 0, out, 1024, 0, b_mlp, x2, 0, 1.0f, 4096);
}

// Round 3
// 565.056 us; speedup vs baseline: 1.2162x; 1.0399x over previous
//
#include <hip/hip_runtime.h>

typedef __bf16 bf16;
typedef bf16 bf16x8 __attribute__((ext_vector_type(8)));
typedef bf16 bf16x4 __attribute__((ext_vector_type(4)));
typedef float f32x16 __attribute__((ext_vector_type(16)));

#define C_DIM 1024
#define T_DIM 2048
#define B_DIM 4
#define H_DIM 4096

// ---------------------------------------------------------------------------
// async global -> LDS, 16B per lane. LDS dest is wave-uniform base + lane*16.
// ---------------------------------------------------------------------------
__device__ inline void gld_lds16(const bf16* g, bf16* l) {
    __builtin_amdgcn_global_load_lds(
        (const __attribute__((address_space(1))) unsigned int*)g,
        (__attribute__((address_space(3))) unsigned int*)l,
        16, 0, 0);
}

// fast tanh-gelu: u * sigmoid(1.5957692*u + 0.07135481*u^3)
__device__ inline float fast_gelu(float u) {
    float k2 = 1.5957691216057308f * u + 0.07135480895843475f * u * u * u;
    float t = __expf(-k2);
    return u * __builtin_amdgcn_rcpf(1.0f + t);
}

// ---------------------------------------------------------------------------
// GEMM: C[M,N] = alpha * A[M,K] @ Bt[N,K]^T (+ bias) (+ gelu | + resid)
// EPI: 0 = alpha*acc + bias(optional)           -> OutT
//      1 = gelu(acc + bias)                     -> OutT (bf16)
//      2 = acc + bias + resid (fp32 residual)   -> OutT (float)
// 128x128 tile, 4 waves (2x2), each wave 2x2 of 32x32x16 bf16 MFMA, BK=64.
// LDS layout XOR-swizzled: slot (row, c) holds global chunk (row, c^(row&7)).
// 32x32 layouts: A[m=lane&31][k=(lane>>5)*8+j]; C/D col=lane&31,
// row=(reg&3)+8*(reg>>2)+4*(lane>>5)  [verified m74/m101].
// ---------------------------------------------------------------------------
template <int EPI, typename OutT>
__launch_bounds__(256)
__global__ void gemm_bt(const bf16* __restrict__ A, int lda, long long sA,
                        const bf16* __restrict__ Bt, int ldb, long long sB,
                        OutT* __restrict__ Cout, int ldc, long long sC,
                        const float* __restrict__ bias,
                        const float* __restrict__ resid, long long sR,
                        float alpha, int K) {
    const int z = blockIdx.z;
    A += (long long)z * sA;
    Bt += (long long)z * sB;
    Cout += (long long)z * sC;
    if (resid) resid += (long long)z * sR;

    const int rowBase = blockIdx.x * 128;
    const int colBase = blockIdx.y * 128;

    __shared__ __align__(16) bf16 As[128 * 64];
    __shared__ __align__(16) bf16 Bs[128 * 64];

    const int tid = threadIdx.x;
    const int w = tid >> 6, lane = tid & 63;
    const int wm = w & 1, wn = w >> 1;
    const int ln31 = lane & 31, lh = lane >> 5;

    // staging: 1024 chunks of 16B per matrix, 4 per thread, XOR-swizzled src
    const bf16* aG[4];
    const bf16* bG[4];
    bf16* aL[4];
    bf16* bL[4];
#pragma unroll
    for (int t = 0; t < 4; t++) {
        int p = t * 256 + tid;               // LDS slot id = t*256 + w*64 + lane
        int prow = p >> 3, pcol = p & 7;
        int gcol = pcol ^ (prow & 7);        // swizzle: which global chunk lands here
        aG[t] = A + (size_t)(rowBase + prow) * lda + gcol * 8;
        bG[t] = Bt + (size_t)(colBase + prow) * ldb + gcol * 8;
        int ubase = (t * 256 + w * 64) * 8;  // wave-uniform LDS base (elements)
        aL[t] = As + ubase;
        bL[t] = Bs + ubase;
    }

    f32x16 acc[2][2] = {};

    for (int k0 = 0; k0 < K; k0 += 64) {
        __syncthreads();
#pragma unroll
        for (int t = 0; t < 4; t++) {
            gld_lds16(aG[t], aL[t]);
            gld_lds16(bG[t], bL[t]);
            aG[t] += 64;
            bG[t] += 64;
        }
        __syncthreads();
#pragma unroll
        for (int ks = 0; ks < 4; ks++) {
            bf16x8 af[2], bfv[2];
            const int cc = (ks << 1) | lh;   // 16B-chunk index along K
#pragma unroll
            for (int i = 0; i < 2; i++) {
                int r = wm * 64 + i * 32 + ln31;
                af[i] = *(const bf16x8*)(As + r * 64 + ((cc ^ (r & 7)) << 3));
            }
#pragma unroll
            for (int j = 0; j < 2; j++) {
                int r = wn * 64 + j * 32 + ln31;
                bfv[j] = *(const bf16x8*)(Bs + r * 64 + ((cc ^ (r & 7)) << 3));
            }
#pragma unroll
            for (int i = 0; i < 2; i++)
#pragma unroll
                for (int j = 0; j < 2; j++)
                    acc[i][j] = __builtin_amdgcn_mfma_f32_32x32x16_bf16(af[i], bfv[j], acc[i][j], 0, 0, 0);
        }
    }

    // epilogue. C/D layout: col=lane&31, row=(reg&3)+8*(reg>>2)+4*(lane>>5)
    float bval[2];
#pragma unroll
    for (int j = 0; j < 2; j++)
        bval[j] = bias ? bias[colBase + wn * 64 + j * 32 + ln31] : 0.0f;
#pragma unroll
    for (int i = 0; i < 2; i++) {
        const int rtile = rowBase + wm * 64 + i * 32 + 4 * lh;
#pragma unroll
        for (int j = 0; j < 2; j++) {
            const int col = colBase + wn * 64 + j * 32 + ln31;
#pragma unroll
            for (int reg = 0; reg < 16; reg++) {
                const int row = rtile + (reg & 3) + 8 * (reg >> 2);
                float v = acc[i][j][reg] * alpha + bval[j];
                if constexpr (EPI == 1) {
                    v = fast_gelu(v);
                }
                if constexpr (EPI == 2) {
                    v += resid[(size_t)row * ldc + col];
                }
                Cout[(size_t)row * ldc + col] = (OutT)v;
            }
        }
    }
}

// ---------------------------------------------------------------------------
// LayerNorm over last dim (C=1024), fp32 in -> bf16 out. One block per row.
// ---------------------------------------------------------------------------
__launch_bounds__(256)
__global__ void ln_kernel(const float* __restrict__ x, const float* __restrict__ g,
                          const float* __restrict__ b, bf16* __restrict__ out) {
    __shared__ float red[4];
    const int row = blockIdx.x;
    const int tid = threadIdx.x;
    const float4* xr = (const float4*)(x + (size_t)row * C_DIM);
    float4 v = xr[tid];
    float s = v.x + v.y + v.z + v.w;
#pragma unroll
    for (int m = 32; m; m >>= 1) s += __shfl_xor(s, m, 64);
    if ((tid & 63) == 0) red[tid >> 6] = s;
    __syncthreads();
    const float mu = (red[0] + red[1] + red[2] + red[3]) * (1.0f / C_DIM);
    const float dx = v.x - mu, dy = v.y - mu, dz = v.z - mu, dw = v.w - mu;
    float q = dx * dx + dy * dy + dz * dz + dw * dw;
#pragma unroll
    for (int m = 32; m; m >>= 1) q += __shfl_xor(q, m, 64);
    __syncthreads();
    if ((tid & 63) == 0) red[tid >> 6] = q;
    __syncthreads();
    const float var = (red[0] + red[1] + red[2] + red[3]) * (1.0f / C_DIM);
    const float rs = rsqrtf(var + 1e-5f);
    const float4 gg = ((const float4*)g)[tid];
    const float4 bb = ((const float4*)b)[tid];
    bf16x4 o;
    o[0] = (bf16)(dx * rs * gg.x + bb.x);
    o[1] = (bf16)(dy * rs * gg.y + bb.y);
    o[2] = (bf16)(dz * rs * gg.z + bb.z);
    o[3] = (bf16)(dw * rs * gg.w + bb.w);
    ((bf16x4*)(out + (size_t)row * C_DIM))[tid] = o;
}

// ---------------------------------------------------------------------------
// Row softmax: S row (T=2048 fp32) -> P row (bf16). One block per row.
// ---------------------------------------------------------------------------
__launch_bounds__(256)
__global__ void softmax_kernel(const float* __restrict__ S, bf16* __restrict__ P) {
    __shared__ float red[4];
    const size_t base = (size_t)blockIdx.x * T_DIM;
    const int tid = threadIdx.x;
    const float4* sr = (const float4*)(S + base);
    float4 v0 = sr[tid];
    float4 v1 = sr[tid + 256];
    float mx = fmaxf(fmaxf(fmaxf(v0.x, v0.y), fmaxf(v0.z, v0.w)),
                     fmaxf(fmaxf(v1.x, v1.y), fmaxf(v1.z, v1.w)));
#pragma unroll
    for (int m = 32; m; m >>= 1) mx = fmaxf(mx, __shfl_xor(mx, m, 64));
    if ((tid & 63) == 0) red[tid >> 6] = mx;
    __syncthreads();
    mx = fmaxf(fmaxf(red[0], red[1]), fmaxf(red[2], red[3]));
    float e[8];
    e[0] = __expf(v0.x - mx); e[1] = __expf(v0.y - mx);
    e[2] = __expf(v0.z - mx); e[3] = __expf(v0.w - mx);
    e[4] = __expf(v1.x - mx); e[5] = __expf(v1.y - mx);
    e[6] = __expf(v1.z - mx); e[7] = __expf(v1.w - mx);
    float s = e[0] + e[1] + e[2] + e[3] + e[4] + e[5] + e[6] + e[7];
#pragma unroll
    for (int m = 32; m; m >>= 1) s += __shfl_xor(s, m, 64);
    __syncthreads();
    if ((tid & 63) == 0) red[tid >> 6] = s;
    __syncthreads();
    const float inv = 1.0f / (red[0] + red[1] + red[2] + red[3]);
    bf16x4 p0, p1;
#pragma unroll
    for (int i = 0; i < 4; i++) {
        p0[i] = (bf16)(e[i] * inv);
        p1[i] = (bf16)(e[4 + i] * inv);
    }
    ((bf16x4*)(P + base))[tid] = p0;
    ((bf16x4*)(P + base))[tid + 256] = p1;
}

// ---------------------------------------------------------------------------
// Merged transpose+convert for all 4 weight matrices (fp32 [R,Cc] -> bf16 [Cc,R]).
// Tile counts: w_attn 96x32=3072, w_proj 32x32=1024, w_fc 128x32=4096,
// w_mlp 32x128=4096; total 12288 blocks of 32x8.
// ---------------------------------------------------------------------------
__global__ void transpose_f2b_all(const float* __restrict__ s0, bf16* __restrict__ d0,
                                  const float* __restrict__ s1, bf16* __restrict__ d1,
                                  const float* __restrict__ s2, bf16* __restrict__ d2,
                                  const float* __restrict__ s3, bf16* __restrict__ d3) {
    __shared__ float tile[32][33];
    int id = blockIdx.x;
    const float* src;
    bf16* dst;
    int R, Cc, local;
    if (id < 3072)       { src = s0; dst = d0; R = 1024; Cc = 3072; local = id; }
    else if (id < 4096)  { src = s1; dst = d1; R = 1024; Cc = 1024; local = id - 3072; }
    else if (id < 8192)  { src = s2; dst = d2; R = 1024; Cc = 4096; local = id - 4096; }
    else                 { src = s3; dst = d3; R = 4096; Cc = 1024; local = id - 8192; }
    const int tilesX = Cc >> 5;
    const int bx = (local % tilesX) * 32;
    const int by = (local / tilesX) * 32;
    const int tx = threadIdx.x, ty = threadIdx.y;
    for (int i = ty; i < 32; i += 8)
        tile[i][tx] = src[(size_t)(by + i) * Cc + bx + tx];
    __syncthreads();
    for (int i = ty; i < 32; i += 8)
        dst[(size_t)(bx + i) * R + by + tx] = (bf16)tile[tx][i];
}

// Transpose bf16 [R, Cc] (ld=ldsrc) -> bf16 [Cc, R] (ld=R), batched via z.
__global__ void transpose_b2b(const bf16* __restrict__ src, int ldsrc, long long sstride,
                              bf16* __restrict__ dst, long long dstride, int R) {
    __shared__ bf16 tile[32][33];
    src += (long long)blockIdx.z * sstride;
    dst += (long long)blockIdx.z * dstride;
    const int bx = blockIdx.x * 32;
    const int by = blockIdx.y * 32;
    const int tx = threadIdx.x, ty = threadIdx.y;
    for (int i = ty; i < 32; i += 8)
        tile[i][tx] = src[(size_t)(by + i) * ldsrc + bx + tx];
    __syncthreads();
    for (int i = ty; i < 32; i += 8)
        dst[(size_t)(bx + i) * R + by + tx] = tile[tx][i];
}

// ---------------------------------------------------------------------------
extern "C" void kernel_launch(void* const* d_in, const int* in_sizes, int n_in,
                              void* d_out, int out_size, void* d_ws, size_t ws_size,
                              hipStream_t stream) {
    const float* x      = (const float*)d_in[0];
    const float* ln1_g  = (const float*)d_in[1];
    const float* ln1_b  = (const float*)d_in[2];
    const float* w_attn = (const float*)d_in[3];
    const float* b_attn = (const float*)d_in[4];
    const float* w_proj = (const float*)d_in[5];
    const float* b_proj = (const float*)d_in[6];
    const float* ln2_g  = (const float*)d_in[7];
    const float* ln2_b  = (const float*)d_in[8];
    const float* w_fc   = (const float*)d_in[9];
    const float* b_fc   = (const float*)d_in[10];
    const float* w_mlp  = (const float*)d_in[11];
    const float* b_mlp  = (const float*)d_in[12];
    float* out = (float*)d_out;

    const int M = B_DIM * T_DIM;  // 8192

    char* base = (char*)d_ws;
    size_t off = 0;
    auto alloc = [&](size_t bytes) -> char* {
        char* p = base + off;
        off += (bytes + 255) & ~(size_t)255;
        return p;
    };
    bf16* wT_attn = (bf16*)alloc((size_t)3072 * 1024 * 2);
    bf16* wT_proj = (bf16*)alloc((size_t)1024 * 1024 * 2);
    bf16* wT_fc   = (bf16*)alloc((size_t)4096 * 1024 * 2);
    bf16* wT_mlp  = (bf16*)alloc((size_t)1024 * 4096 * 2);
    bf16* h       = (bf16*)alloc((size_t)M * 1024 * 2);        // h1, reused as h2
    bf16* qkv     = (bf16*)alloc((size_t)M * 3072 * 2);
    bf16* vT      = (bf16*)alloc((size_t)B_DIM * 1024 * 2048 * 2);
    float* S      = (float*)alloc((size_t)B_DIM * 2048 * 2048 * 4);
    bf16* P       = (bf16*)alloc((size_t)B_DIM * 2048 * 2048 * 2);
    bf16* y       = (bf16*)alloc((size_t)M * 1024 * 2);
    float* x2     = (float*)alloc((size_t)M * 1024 * 4);
    bf16* act     = (bf16*)S;  // alias: S dead after softmax; sizes match (67MB)

    const dim3 tb(32, 8);

    // weight transpose+convert, all 4 in one launch
    transpose_f2b_all<<<12288, tb, 0, stream>>>(w_attn, wT_attn, w_proj, wT_proj,
                                                w_fc, wT_fc, w_mlp, wT_mlp);

    // h = LN1(x)
    ln_kernel<<<M, 256, 0, stream>>>(x, ln1_g, ln1_b, h);

    // qkv = h @ w_attn + b_attn   [8192, 3072]
    gemm_bt<0, bf16><<<dim3(64, 24, 1), 256, 0, stream>>>(
        h, 1024, 0, wT_attn, 1024, 0, qkv, 3072, 0, b_attn, nullptr, 0, 1.0f, 1024);

    // vT[b] = v[b]^T   (v = qkv cols [2C,3C))
    transpose_b2b<<<dim3(1024 / 32, 2048 / 32, B_DIM), tb, 0, stream>>>(
        qkv + 2 * C_DIM, 3072, (long long)T_DIM * 3072, vT, (long long)C_DIM * T_DIM, T_DIM);

    // S[b] = q[b] @ k[b]^T * (1/32)   [2048, 2048] fp32
    gemm_bt<0, float><<<dim3(16, 16, B_DIM), 256, 0, stream>>>(
        qkv, 3072, (long long)T_DIM * 3072,
        qkv + C_DIM, 3072, (long long)T_DIM * 3072,
        S, 2048, (long long)T_DIM * T_DIM, nullptr, nullptr, 0, 0.03125f, 1024);

    // P = softmax(S) rows
    softmax_kernel<<<B_DIM * T_DIM, 256, 0, stream>>>(S, P);

    // y[b] = P[b] @ v[b]   [2048, 1024] bf16
    gemm_bt<0, bf16><<<dim3(16, 8, B_DIM), 256, 0, stream>>>(
        P, 2048, (long long)T_DIM * T_DIM,
        vT, 2048, (long long)C_DIM * T_DIM,
        y, 1024, (long long)T_DIM * C_DIM, nullptr, nullptr, 0, 1.0f, 2048);

    // x2 = y @ w_proj + b_proj + x   [8192, 1024] fp32
    gemm_bt<2, float><<<dim3(64, 8, 1), 256, 0, stream>>>(
        y, 1024, 0, wT_proj, 1024, 0, x2, 1024, 0, b_proj, x, 0, 1.0f, 1024);

    // h2 = LN2(x2)  (reuse h buffer)
    ln_kernel<<<M, 256, 0, stream>>>(x2, ln2_g, ln2_b, h);

    // act = gelu(h2 @ w_fc + b_fc)   [8192, 4096] bf16
    gemm_bt<1, bf16><<<dim3(64, 32, 1), 256, 0, stream>>>(
        h, 1024, 0, wT_fc, 1024, 0, act, 4096, 0, b_fc, nullptr, 0, 1.0f, 1024);

    // out = act @ w_mlp_proj + b_mlp_proj + x2   [8192, 1024] fp32
    gemm_bt<2, float><<<dim3(64, 8, 1), 256, 0, stream>>>(
        act, 4096, 0, wT_mlp, 4096, 0, out, 1024, 0, b_mlp, x2, 0, 1.0f, 4096);
}

// Round 4
// 515.695 us; speedup vs baseline: 1.3326x; 1.0957x over previous
//
#include <hip/hip_runtime.h>

typedef __bf16 bf16;
typedef bf16 bf16x8 __attribute__((ext_vector_type(8)));
typedef bf16 bf16x4 __attribute__((ext_vector_type(4)));
typedef float f32x16 __attribute__((ext_vector_type(16)));

#define C_DIM 1024
#define T_DIM 2048
#define B_DIM 4
#define H_DIM 4096

// ---------------------------------------------------------------------------
// async global -> LDS, 16B per lane. LDS dest is wave-uniform base + lane*16.
// ---------------------------------------------------------------------------
__device__ inline void gld_lds16(const bf16* g, bf16* l) {
    __builtin_amdgcn_global_load_lds(
        (const __attribute__((address_space(1))) unsigned int*)g,
        (__attribute__((address_space(3))) unsigned int*)l,
        16, 0, 0);
}

// fast tanh-gelu: u * sigmoid(1.5957692*u + 0.07135481*u^3)
__device__ inline float fast_gelu(float u) {
    float k2 = 1.5957691216057308f * u + 0.07135480895843475f * u * u * u;
    float t = __expf(-k2);
    return u * __builtin_amdgcn_rcpf(1.0f + t);
}

// ---------------------------------------------------------------------------
// GEMM: C[M,N] = alpha * A[M,K] @ Bt[N,K]^T (+ bias) (+ gelu | + resid)
// EPI: 0 = alpha*acc + bias(optional)           -> OutT
//      1 = gelu(acc + bias)                     -> OutT (bf16)
//      2 = acc + bias + resid (fp32 residual)   -> OutT (float)
// 128x128 tile, 4 waves (2x2), each wave 2x2 of 32x32x16 bf16 MFMA, BK=64.
// LDS layout XOR-swizzled: slot (row, c) holds global chunk (row, c^(row&7)).
// Register-trimmed staging: one per-lane element offset + uniform t/k terms
// (SGPR-foldable) instead of 8 persistent 64-bit pointers.
// ---------------------------------------------------------------------------
template <int EPI, typename OutT>
__launch_bounds__(256, 3)
__global__ void gemm_bt(const bf16* __restrict__ A, int lda, long long sA,
                        const bf16* __restrict__ Bt, int ldb, long long sB,
                        OutT* __restrict__ Cout, int ldc, long long sC,
                        const float* __restrict__ bias,
                        const float* __restrict__ resid, long long sR,
                        float alpha, int K) {
    const int z = blockIdx.z;
    A += (long long)z * sA;
    Bt += (long long)z * sB;
    Cout += (long long)z * sC;
    if (resid) resid += (long long)z * sR;

    const int rowBase = blockIdx.x * 128;
    const int colBase = blockIdx.y * 128;

    __shared__ __align__(16) bf16 As[128 * 64];
    __shared__ __align__(16) bf16 Bs[128 * 64];

    const int tid = threadIdx.x;
    const int w = tid >> 6, lane = tid & 63;
    const int wm = w & 1, wn = w >> 1;
    const int ln31 = lane & 31, lh = lane >> 5;

    // per-lane staging offset (elements): row (tid>>3), swizzled chunk
    const int srow = tid >> 3;
    const int scol = ((tid & 7) ^ (srow & 7)) << 3;
    const bf16* Abase = A + (size_t)(rowBase + srow) * lda + scol;
    const bf16* Bbase = Bt + (size_t)(colBase + srow) * ldb + scol;
    bf16* ldsA = As + (size_t)(w * 64) * 8;   // + t*2048 per t
    bf16* ldsB = Bs + (size_t)(w * 64) * 8;

    // fragment read bases
    const int rA = wm * 64 + ln31;
    const int rB = wn * 64 + ln31;
    const int swA = rA & 7, swB = rB & 7;

    f32x16 acc[2][2] = {};

    for (int k0 = 0; k0 < K; k0 += 64) {
        __syncthreads();
#pragma unroll
        for (int t = 0; t < 4; t++) {
            gld_lds16(Abase + (size_t)(t * 32) * lda + k0, ldsA + t * 2048);
            gld_lds16(Bbase + (size_t)(t * 32) * ldb + k0, ldsB + t * 2048);
        }
        __syncthreads();
#pragma unroll
        for (int ks = 0; ks < 4; ks++) {
            bf16x8 af[2], bfv[2];
            const int cc = (ks << 1) | lh;   // 16B-chunk index along K
#pragma unroll
            for (int i = 0; i < 2; i++)
                af[i] = *(const bf16x8*)(As + (rA + i * 32) * 64 + ((cc ^ swA) << 3));
#pragma unroll
            for (int j = 0; j < 2; j++)
                bfv[j] = *(const bf16x8*)(Bs + (rB + j * 32) * 64 + ((cc ^ swB) << 3));
#pragma unroll
            for (int i = 0; i < 2; i++)
#pragma unroll
                for (int j = 0; j < 2; j++)
                    acc[i][j] = __builtin_amdgcn_mfma_f32_32x32x16_bf16(af[i], bfv[j], acc[i][j], 0, 0, 0);
        }
    }

    // epilogue. C/D layout: col=lane&31, row=(reg&3)+8*(reg>>2)+4*(lane>>5)
    float bval[2];
#pragma unroll
    for (int j = 0; j < 2; j++)
        bval[j] = bias ? bias[colBase + wn * 64 + j * 32 + ln31] : 0.0f;
#pragma unroll
    for (int i = 0; i < 2; i++) {
        const int rtile = rowBase + wm * 64 + i * 32 + 4 * lh;
#pragma unroll
        for (int j = 0; j < 2; j++) {
            const int col = colBase + wn * 64 + j * 32 + ln31;
#pragma unroll
            for (int reg = 0; reg < 16; reg++) {
                const int row = rtile + (reg & 3) + 8 * (reg >> 2);
                float v = acc[i][j][reg] * alpha + bval[j];
                if constexpr (EPI == 1) {
                    v = fast_gelu(v);
                }
                if constexpr (EPI == 2) {
                    v += resid[(size_t)row * ldc + col];
                }
                Cout[(size_t)row * ldc + col] = (OutT)v;
            }
        }
    }
}

// ---------------------------------------------------------------------------
// LayerNorm over last dim (C=1024), fp32 in -> bf16 out. One block per row.
// ---------------------------------------------------------------------------
__launch_bounds__(256)
__global__ void ln_kernel(const float* __restrict__ x, const float* __restrict__ g,
                          const float* __restrict__ b, bf16* __restrict__ out) {
    __shared__ float red[4];
    const int row = blockIdx.x;
    const int tid = threadIdx.x;
    const float4* xr = (const float4*)(x + (size_t)row * C_DIM);
    float4 v = xr[tid];
    float s = v.x + v.y + v.z + v.w;
#pragma unroll
    for (int m = 32; m; m >>= 1) s += __shfl_xor(s, m, 64);
    if ((tid & 63) == 0) red[tid >> 6] = s;
    __syncthreads();
    const float mu = (red[0] + red[1] + red[2] + red[3]) * (1.0f / C_DIM);
    const float dx = v.x - mu, dy = v.y - mu, dz = v.z - mu, dw = v.w - mu;
    float q = dx * dx + dy * dy + dz * dz + dw * dw;
#pragma unroll
    for (int m = 32; m; m >>= 1) q += __shfl_xor(q, m, 64);
    __syncthreads();
    if ((tid & 63) == 0) red[tid >> 6] = q;
    __syncthreads();
    const float var = (red[0] + red[1] + red[2] + red[3]) * (1.0f / C_DIM);
    const float rs = rsqrtf(var + 1e-5f);
    const float4 gg = ((const float4*)g)[tid];
    const float4 bb = ((const float4*)b)[tid];
    bf16x4 o;
    o[0] = (bf16)(dx * rs * gg.x + bb.x);
    o[1] = (bf16)(dy * rs * gg.y + bb.y);
    o[2] = (bf16)(dz * rs * gg.z + bb.z);
    o[3] = (bf16)(dw * rs * gg.w + bb.w);
    ((bf16x4*)(out + (size_t)row * C_DIM))[tid] = o;
}

// ---------------------------------------------------------------------------
// Row softmax: S row (T=2048 bf16) -> P row (bf16). One block per row.
// ---------------------------------------------------------------------------
__launch_bounds__(256)
__global__ void softmax_kernel(const bf16* __restrict__ S, bf16* __restrict__ P) {
    __shared__ float red[4];
    const size_t base = (size_t)blockIdx.x * T_DIM;
    const int tid = threadIdx.x;
    bf16x8 sv = ((const bf16x8*)(S + base))[tid];
    float e[8];
#pragma unroll
    for (int i = 0; i < 8; i++) e[i] = (float)sv[i];
    float mx = e[0];
#pragma unroll
    for (int i = 1; i < 8; i++) mx = fmaxf(mx, e[i]);
#pragma unroll
    for (int m = 32; m; m >>= 1) mx = fmaxf(mx, __shfl_xor(mx, m, 64));
    if ((tid & 63) == 0) red[tid >> 6] = mx;
    __syncthreads();
    mx = fmaxf(fmaxf(red[0], red[1]), fmaxf(red[2], red[3]));
    float s = 0.0f;
#pragma unroll
    for (int i = 0; i < 8; i++) {
        e[i] = __expf(e[i] - mx);
        s += e[i];
    }
#pragma unroll
    for (int m = 32; m; m >>= 1) s += __shfl_xor(s, m, 64);
    __syncthreads();
    if ((tid & 63) == 0) red[tid >> 6] = s;
    __syncthreads();
    const float inv = 1.0f / (red[0] + red[1] + red[2] + red[3]);
    bf16x8 p;
#pragma unroll
    for (int i = 0; i < 8; i++) p[i] = (bf16)(e[i] * inv);
    ((bf16x8*)(P + base))[tid] = p;
}

// ---------------------------------------------------------------------------
// Merged transpose+convert for all 4 weight matrices (fp32 [R,Cc] -> bf16 [Cc,R]).
// ---------------------------------------------------------------------------
__global__ void transpose_f2b_all(const float* __restrict__ s0, bf16* __restrict__ d0,
                                  const float* __restrict__ s1, bf16* __restrict__ d1,
                                  const float* __restrict__ s2, bf16* __restrict__ d2,
                                  const float* __restrict__ s3, bf16* __restrict__ d3) {
    __shared__ float tile[32][33];
    int id = blockIdx.x;
    const float* src;
    bf16* dst;
    int R, Cc, local;
    if (id < 3072)       { src = s0; dst = d0; R = 1024; Cc = 3072; local = id; }
    else if (id < 4096)  { src = s1; dst = d1; R = 1024; Cc = 1024; local = id - 3072; }
    else if (id < 8192)  { src = s2; dst = d2; R = 1024; Cc = 4096; local = id - 4096; }
    else                 { src = s3; dst = d3; R = 4096; Cc = 1024; local = id - 8192; }
    const int tilesX = Cc >> 5;
    const int bx = (local % tilesX) * 32;
    const int by = (local / tilesX) * 32;
    const int tx = threadIdx.x, ty = threadIdx.y;
    for (int i = ty; i < 32; i += 8)
        tile[i][tx] = src[(size_t)(by + i) * Cc + bx + tx];
    __syncthreads();
    for (int i = ty; i < 32; i += 8)
        dst[(size_t)(bx + i) * R + by + tx] = (bf16)tile[tx][i];
}

// Transpose bf16 [R, Cc] (ld=ldsrc) -> bf16 [Cc, R] (ld=R), batched via z.
__global__ void transpose_b2b(const bf16* __restrict__ src, int ldsrc, long long sstride,
                              bf16* __restrict__ dst, long long dstride, int R) {
    __shared__ bf16 tile[32][33];
    src += (long long)blockIdx.z * sstride;
    dst += (long long)blockIdx.z * dstride;
    const int bx = blockIdx.x * 32;
    const int by = blockIdx.y * 32;
    const int tx = threadIdx.x, ty = threadIdx.y;
    for (int i = ty; i < 32; i += 8)
        tile[i][tx] = src[(size_t)(by + i) * ldsrc + bx + tx];
    __syncthreads();
    for (int i = ty; i < 32; i += 8)
        dst[(size_t)(bx + i) * R + by + tx] = tile[tx][i];
}

// ---------------------------------------------------------------------------
extern "C" void kernel_launch(void* const* d_in, const int* in_sizes, int n_in,
                              void* d_out, int out_size, void* d_ws, size_t ws_size,
                              hipStream_t stream) {
    const float* x      = (const float*)d_in[0];
    const float* ln1_g  = (const float*)d_in[1];
    const float* ln1_b  = (const float*)d_in[2];
    const float* w_attn = (const float*)d_in[3];
    const float* b_attn = (const float*)d_in[4];
    const float* w_proj = (const float*)d_in[5];
    const float* b_proj = (const float*)d_in[6];
    const float* ln2_g  = (const float*)d_in[7];
    const float* ln2_b  = (const float*)d_in[8];
    const float* w_fc   = (const float*)d_in[9];
    const float* b_fc   = (const float*)d_in[10];
    const float* w_mlp  = (const float*)d_in[11];
    const float* b_mlp  = (const float*)d_in[12];
    float* out = (float*)d_out;

    const int M = B_DIM * T_DIM;  // 8192

    char* base = (char*)d_ws;
    size_t off = 0;
    auto alloc = [&](size_t bytes) -> char* {
        char* p = base + off;
        off += (bytes + 255) & ~(size_t)255;
        return p;
    };
    bf16* wT_attn = (bf16*)alloc((size_t)3072 * 1024 * 2);
    bf16* wT_proj = (bf16*)alloc((size_t)1024 * 1024 * 2);
    bf16* wT_fc   = (bf16*)alloc((size_t)4096 * 1024 * 2);
    bf16* wT_mlp  = (bf16*)alloc((size_t)1024 * 4096 * 2);
    bf16* h       = (bf16*)alloc((size_t)M * 1024 * 2);        // h1, reused as h2
    bf16* qkv     = (bf16*)alloc((size_t)M * 3072 * 2);
    bf16* vT      = (bf16*)alloc((size_t)B_DIM * 1024 * 2048 * 2);
    bf16* S       = (bf16*)alloc((size_t)B_DIM * 2048 * 2048 * 2);
    bf16* P       = (bf16*)alloc((size_t)B_DIM * 2048 * 2048 * 2);
    bf16* y       = (bf16*)alloc((size_t)M * 1024 * 2);
    float* x2     = (float*)alloc((size_t)M * 1024 * 4);
    bf16* act     = (bf16*)S;  // alias: S+P dead after PV; 67MB needed, S+P = 67MB

    const dim3 tb(32, 8);

    // weight transpose+convert, all 4 in one launch
    transpose_f2b_all<<<12288, tb, 0, stream>>>(w_attn, wT_attn, w_proj, wT_proj,
                                                w_fc, wT_fc, w_mlp, wT_mlp);

    // h = LN1(x)
    ln_kernel<<<M, 256, 0, stream>>>(x, ln1_g, ln1_b, h);

    // qkv = h @ w_attn + b_attn   [8192, 3072]
    gemm_bt<0, bf16><<<dim3(64, 24, 1), 256, 0, stream>>>(
        h, 1024, 0, wT_attn, 1024, 0, qkv, 3072, 0, b_attn, nullptr, 0, 1.0f, 1024);

    // vT[b] = v[b]^T   (v = qkv cols [2C,3C))
    transpose_b2b<<<dim3(1024 / 32, 2048 / 32, B_DIM), tb, 0, stream>>>(
        qkv + 2 * C_DIM, 3072, (long long)T_DIM * 3072, vT, (long long)C_DIM * T_DIM, T_DIM);

    // S[b] = q[b] @ k[b]^T * (1/32)   [2048, 2048] bf16
    gemm_bt<0, bf16><<<dim3(16, 16, B_DIM), 256, 0, stream>>>(
        qkv, 3072, (long long)T_DIM * 3072,
        qkv + C_DIM, 3072, (long long)T_DIM * 3072,
        S, 2048, (long long)T_DIM * T_DIM, nullptr, nullptr, 0, 0.03125f, 1024);

    // P = softmax(S) rows
    softmax_kernel<<<B_DIM * T_DIM, 256, 0, stream>>>(S, P);

    // y[b] = P[b] @ v[b]   [2048, 1024] bf16
    gemm_bt<0, bf16><<<dim3(16, 8, B_DIM), 256, 0, stream>>>(
        P, 2048, (long long)T_DIM * T_DIM,
        vT, 2048, (long long)C_DIM * T_DIM,
        y, 1024, (long long)T_DIM * C_DIM, nullptr, nullptr, 0, 1.0f, 2048);

    // x2 = y @ w_proj + b_proj + x   [8192, 1024] fp32
    gemm_bt<2, float><<<dim3(64, 8, 1), 256, 0, stream>>>(
        y, 1024, 0, wT_proj, 1024, 0, x2, 1024, 0, b_proj, x, 0, 1.0f, 1024);

    // h2 = LN2(x2)  (reuse h buffer)
    ln_kernel<<<M, 256, 0, stream>>>(x2, ln2_g, ln2_b, h);

    // act = gelu(h2 @ w_fc + b_fc)   [8192, 4096] bf16
    gemm_bt<1, bf16><<<dim3(64, 32, 1), 256, 0, stream>>>(
        h, 1024, 0, wT_fc, 1024, 0, act, 4096, 0, b_fc, nullptr, 0, 1.0f, 1024);

    // out = act @ w_mlp_proj + b_mlp_proj + x2   [8192, 1024] fp32
    gemm_bt<2, float><<<dim3(64, 8, 1), 256, 0, stream>>>(
        act, 4096, 0, wT_mlp, 4096, 0, out, 1024, 0, b_mlp, x2, 0, 1.0f, 4096);
}